// Round 10
// baseline (118.909 us; speedup 1.0000x reference)
//
#include <hip/hip_runtime.h>
#include <math.h>

#define B_   8
#define M_   4096
#define N_   4096
#define DM   1024
#define DC   768
#define DH   16
#define CHUNKS 64
#define CW    64          // chunk width in cols
#define XSTRIDE 68        // CW + 4 pad (bank skew)

typedef float v4f __attribute__((ext_vector_type(4)));

__device__ __forceinline__ float elu1(float t) {
    return t > 0.0f ? t + 1.0f : expf(t);
}
__device__ __forceinline__ float4 ld4(const float* p) { return *reinterpret_cast<const float4*>(p); }
__device__ __forceinline__ void  st4(float* p, float4 v) { *reinterpret_cast<float4*>(p) = v; }
__device__ __forceinline__ void  st4nt(float* p, float4 v) {
    v4f w; w.x = v.x; w.y = v.y; w.z = v.z; w.w = v.w;
    __builtin_nontemporal_store(w, reinterpret_cast<v4f*>(p));
}
__device__ __forceinline__ float4 sx4(float4 v, int m) {
    float4 r;
    r.x = __shfl_xor(v.x, m); r.y = __shfl_xor(v.y, m);
    r.z = __shfl_xor(v.z, m); r.w = __shfl_xor(v.w, m);
    return r;
}
__device__ __forceinline__ float4 add4(float4 a, float4 b) {
    float4 r; r.x=a.x+b.x; r.y=a.y+b.y; r.z=a.z+b.z; r.w=a.w+b.w; return r;
}
__device__ __forceinline__ void fma4(float4& a, float s, float4 w) {
    a.x = fmaf(s, w.x, a.x); a.y = fmaf(s, w.y, a.y);
    a.z = fmaf(s, w.z, a.z); a.w = fmaf(s, w.w, a.w);
}

// ---------------------------------------------------------------------------
// fused1: blocks [0,512): kvr — K=elu1(ctx@Wk+bk), V=ctx@Wv+bv (LDS only),
//                         fused partial KtV(16x16)+Ksum -> part.
//         blocks [512,1024): Q = elu1(x@Wq+bq) -> q_ws.
// LDS = 17.4 KB (sk/sv union'd into xt); __launch_bounds__(256,4) caps VGPR
// at 128 -> 4 blocks/CU resident, grid 1024 = exactly one resident round.
// ---------------------------------------------------------------------------
__global__ __launch_bounds__(256, 4) void fused1(
    const float* __restrict__ ctx,
    const float* __restrict__ Wk, const float* __restrict__ bk,
    const float* __restrict__ Wv, const float* __restrict__ bv,
    const float* __restrict__ x,
    const float* __restrict__ Wq, const float* __restrict__ bq,
    float* __restrict__ part, float* __restrict__ q_ws)
{
    __shared__ union {
        float xt[64 * XSTRIDE];                       // 17408 B
        struct { float k[64][DH]; float v[64][DH]; } kv;  // 8192 B (post-loop)
    } sh;

    const int t = threadIdx.x;
    const int q = t & 3;
    const int s = (t >> 2) & 3;
    const int g = t >> 4;
    const int rs = t >> 4;           // staging rows rs + i*16
    const int cs = (t & 15) * 4;     // staging col

    if (blockIdx.x < B_*N_/64) {
        // ---------------- kvr path (12 chunks of 64 cols) ----------------
        const size_t row0 = (size_t)blockIdx.x * 64;
        float4 ka[4], va[4];
        #pragma unroll
        for (int r = 0; r < 4; ++r) { ka[r] = make_float4(0,0,0,0); va[r] = make_float4(0,0,0,0); }
        float4 A[4];

#define SLOAD(ch) { \
        _Pragma("unroll") for (int i = 0; i < 4; ++i) \
            A[i] = ld4(ctx + (row0 + rs + i*16)*DC + (ch)*CW + cs); }
#define SWRITE() { \
        _Pragma("unroll") for (int i = 0; i < 4; ++i) \
            st4(&sh.xt[(rs + i*16)*XSTRIDE + cs], A[i]); }

        SLOAD(0);
        for (int ch = 0; ch < DC/CW; ++ch) {
            SWRITE();
            __syncthreads();
            if (ch + 1 < DC/CW) SLOAD(ch + 1);   // in flight during compute

            #pragma unroll
            for (int kk = 0; kk < 4; ++kk) {
                const int kl = kk*16 + s*4;
                const int kg = ch*CW + kl;
                const float4 wk0 = ld4(Wk + (size_t)(kg+0)*DH + q*4);
                const float4 wk1 = ld4(Wk + (size_t)(kg+1)*DH + q*4);
                const float4 wk2 = ld4(Wk + (size_t)(kg+2)*DH + q*4);
                const float4 wk3 = ld4(Wk + (size_t)(kg+3)*DH + q*4);
                const float4 wv0 = ld4(Wv + (size_t)(kg+0)*DH + q*4);
                const float4 wv1 = ld4(Wv + (size_t)(kg+1)*DH + q*4);
                const float4 wv2 = ld4(Wv + (size_t)(kg+2)*DH + q*4);
                const float4 wv3 = ld4(Wv + (size_t)(kg+3)*DH + q*4);
                #pragma unroll
                for (int r = 0; r < 4; ++r) {
                    const float4 xv = ld4(&sh.xt[(g*4 + r)*XSTRIDE + kl]);
                    fma4(ka[r], xv.x, wk0); fma4(ka[r], xv.y, wk1);
                    fma4(ka[r], xv.z, wk2); fma4(ka[r], xv.w, wk3);
                    fma4(va[r], xv.x, wv0); fma4(va[r], xv.y, wv1);
                    fma4(va[r], xv.z, wv2); fma4(va[r], xv.w, wv3);
                }
            }
            __syncthreads();
        }
#undef SLOAD
#undef SWRITE

        #pragma unroll
        for (int r = 0; r < 4; ++r) {
            ka[r] = add4(ka[r], sx4(ka[r], 4)); ka[r] = add4(ka[r], sx4(ka[r], 8));
            va[r] = add4(va[r], sx4(va[r], 4)); va[r] = add4(va[r], sx4(va[r], 8));
        }

        // xt is dead (last chunk barrier passed) — reuse as sk/sv
        if (s == 0) {
            const float4 b4 = ld4(bk + q*4);
            #pragma unroll
            for (int r = 0; r < 4; ++r) {
                float4 o;
                o.x = elu1(ka[r].x + b4.x); o.y = elu1(ka[r].y + b4.y);
                o.z = elu1(ka[r].z + b4.z); o.w = elu1(ka[r].w + b4.w);
                st4(&sh.kv.k[g*4 + r][q*4], o);
            }
        } else if (s == 1) {
            const float4 b4 = ld4(bv + q*4);
            #pragma unroll
            for (int r = 0; r < 4; ++r) {
                float4 o;
                o.x = va[r].x + b4.x; o.y = va[r].y + b4.y;
                o.z = va[r].z + b4.z; o.w = va[r].w + b4.w;
                st4(&sh.kv.v[g*4 + r][q*4], o);
            }
        }
        __syncthreads();

        const int d = t >> 4, e = t & 15;
        float acc = 0.f;
        #pragma unroll 16
        for (int n = 0; n < 64; ++n) acc += sh.kv.k[n][d] * sh.kv.v[n][e];
        float* p = part + (size_t)blockIdx.x * 272;
        p[t] = acc;
        if (t < DH) {
            float ss = 0.f;
            #pragma unroll 16
            for (int n = 0; n < 64; ++n) ss += sh.kv.k[n][t];
            p[256 + t] = ss;
        }
    } else {
        // ---------------- Q path (16 chunks of 64 cols) ----------------
        const size_t row0 = (size_t)(blockIdx.x - B_*N_/64) * 64;
        float4 a4[4];
        #pragma unroll
        for (int r = 0; r < 4; ++r) a4[r] = make_float4(0,0,0,0);
        float4 A[4];

#define SLOAD(ch) { \
        _Pragma("unroll") for (int i = 0; i < 4; ++i) \
            A[i] = ld4(x + (row0 + rs + i*16)*DM + (ch)*CW + cs); }
#define SWRITE() { \
        _Pragma("unroll") for (int i = 0; i < 4; ++i) \
            st4(&sh.xt[(rs + i*16)*XSTRIDE + cs], A[i]); }

        SLOAD(0);
        for (int ch = 0; ch < DM/CW; ++ch) {
            SWRITE();
            __syncthreads();
            if (ch + 1 < DM/CW) SLOAD(ch + 1);

            #pragma unroll
            for (int kk = 0; kk < 4; ++kk) {
                const int kl = kk*16 + s*4;
                const int kg = ch*CW + kl;
                const float4 w0 = ld4(Wq + (size_t)(kg+0)*DH + q*4);
                const float4 w1 = ld4(Wq + (size_t)(kg+1)*DH + q*4);
                const float4 w2 = ld4(Wq + (size_t)(kg+2)*DH + q*4);
                const float4 w3 = ld4(Wq + (size_t)(kg+3)*DH + q*4);
                #pragma unroll
                for (int r = 0; r < 4; ++r) {
                    const float4 xv = ld4(&sh.xt[(g*4 + r)*XSTRIDE + kl]);
                    fma4(a4[r], xv.x, w0); fma4(a4[r], xv.y, w1);
                    fma4(a4[r], xv.z, w2); fma4(a4[r], xv.w, w3);
                }
            }
            __syncthreads();
        }
#undef SLOAD
#undef SWRITE

        #pragma unroll
        for (int r = 0; r < 4; ++r) {
            a4[r] = add4(a4[r], sx4(a4[r], 4));
            a4[r] = add4(a4[r], sx4(a4[r], 8));
        }

        if (s == 0) {
            const float4 b4 = ld4(bq + q*4);
            #pragma unroll
            for (int r = 0; r < 4; ++r) {
                float4 o;
                o.x = elu1(a4[r].x + b4.x); o.y = elu1(a4[r].y + b4.y);
                o.z = elu1(a4[r].z + b4.z); o.w = elu1(a4[r].w + b4.w);
                st4(q_ws + (row0 + g*4 + r)*DH + q*4, o);
            }
        }
    }
}

// ---------------------------------------------------------------------------
// reduce2: combine partials -> comb[b][272] (256 KtV d-major + 16 Ksum)
// ---------------------------------------------------------------------------
__global__ __launch_bounds__(320) void reduce2(
    const float* __restrict__ part, float* __restrict__ comb)
{
    const int b = blockIdx.x;
    const int t = threadIdx.x;
    if (t < 272) {
        float s = 0.f;
        #pragma unroll
        for (int ch = 0; ch < CHUNKS; ++ch)
            s += part[((size_t)b*CHUNKS + ch) * 272 + t];
        comb[(size_t)b*272 + t] = s;
    }
}

// ---------------------------------------------------------------------------
// oproj: o = (Q@KtV)/(Q.Ksum+1e-6); out = o@Wo + bo.
// 16 rows/block, grid = B*M/16 = 2048. Wo in regs, nt coalesced stores.
// ---------------------------------------------------------------------------
__global__ __launch_bounds__(256) void oproj(
    const float* __restrict__ q_ws, const float* __restrict__ comb,
    const float* __restrict__ Wo, const float* __restrict__ bo,
    float* __restrict__ out)
{
    __shared__ float ql[16 * DH];
    __shared__ float ol[16 * DH];
    __shared__ float kts[272];

    const int t = threadIdx.x;
    const size_t row0 = (size_t)blockIdx.x * 16;
    const int b = blockIdx.x >> 8;          // 256 blocks per batch

    float4 wreg[16];
    #pragma unroll
    for (int e = 0; e < 16; ++e) wreg[e] = ld4(Wo + (size_t)e*DM + t*4);
    const float4 bov = ld4(bo + t*4);

    if (t < 64) st4(&ql[t*4], ld4(q_ws + row0*DH + t*4));
    else if (t < 132) st4(&kts[(t-64)*4], ld4(comb + (size_t)b*272 + (t-64)*4));
    __syncthreads();

    if (t < 64) {
        const float* qrow = &ql[(t >> 2) * DH];
        const int jj = (t & 3) * 4;
        float den = 1e-6f;
        float4 num = make_float4(0,0,0,0);
        #pragma unroll
        for (int d4 = 0; d4 < 4; ++d4) {
            const float4 q4  = ld4(&qrow[d4*4]);
            const float4 ks4 = ld4(&kts[256 + d4*4]);
            den += q4.x*ks4.x + q4.y*ks4.y + q4.z*ks4.z + q4.w*ks4.w;
            fma4(num, q4.x, ld4(&kts[(d4*4+0)*DH + jj]));
            fma4(num, q4.y, ld4(&kts[(d4*4+1)*DH + jj]));
            fma4(num, q4.z, ld4(&kts[(d4*4+2)*DH + jj]));
            fma4(num, q4.w, ld4(&kts[(d4*4+3)*DH + jj]));
        }
        const float inv = 1.0f / den;
        float4 o4; o4.x = num.x*inv; o4.y = num.y*inv; o4.z = num.z*inv; o4.w = num.w*inv;
        st4(&ol[(t >> 2)*DH + jj], o4);
    }
    __syncthreads();

    #pragma unroll
    for (int r = 0; r < 16; ++r) {
        float4 a = bov;
        #pragma unroll
        for (int eo = 0; eo < 4; ++eo) {
            const float4 o4 = ld4(&ol[r*DH + eo*4]);
            fma4(a, o4.x, wreg[eo*4+0]); fma4(a, o4.y, wreg[eo*4+1]);
            fma4(a, o4.z, wreg[eo*4+2]); fma4(a, o4.w, wreg[eo*4+3]);
        }
        st4nt(out + (row0 + r)*DM + t*4, a);
    }
}

// ---------------------------------------------------------------------------
extern "C" void kernel_launch(void* const* d_in, const int* in_sizes, int n_in,
                              void* d_out, int out_size, void* d_ws, size_t ws_size,
                              hipStream_t stream) {
    const float* x    = (const float*)d_in[0];
    const float* ctx  = (const float*)d_in[1];
    const float* Wq   = (const float*)d_in[2];
    const float* bq   = (const float*)d_in[3];
    const float* Wk   = (const float*)d_in[4];
    const float* bk   = (const float*)d_in[5];
    const float* Wv   = (const float*)d_in[6];
    const float* bv   = (const float*)d_in[7];
    const float* Wo   = (const float*)d_in[8];
    const float* bo   = (const float*)d_in[9];
    float* out = (float*)d_out;

    float* ws = (float*)d_ws;
    float* part = ws;                               // 512*272
    float* comb = part + (size_t)512*272;           // 8*272
    float* q_ws = comb + (size_t)B_*272;            // 32768*16 = 2 MB

    fused1<<<dim3(B_*N_/64 + B_*M_/64), dim3(256), 0, stream>>>(
        ctx, Wk, bk, Wv, bv, x, Wq, bq, part, q_ws);
    reduce2<<<dim3(B_), dim3(320), 0, stream>>>(part, comb);
    oproj<<<dim3(B_*M_/16), dim3(256), 0, stream>>>(q_ws, comb, Wo, bo, out);
}

// Round 11
// 82.382 us; speedup vs baseline: 1.4434x; 1.4434x over previous
//
#include <hip/hip_runtime.h>
#include <math.h>

#define B_   8
#define M_   4096
#define N_   4096
#define DM   1024
#define DC   768
#define DH   16
#define CHUNKS 64
#define XS   136         // bf16 per LDS row: 128 data + 8 pad (272B, 16B-aligned)
#define NCHQ (DM/128)    // 8
#define NCHK (DC/128)    // 6

typedef float v4f __attribute__((ext_vector_type(4)));
typedef __attribute__((ext_vector_type(8))) short short8v;   // 8 bf16 (4 VGPR)
typedef __attribute__((ext_vector_type(4))) float f32x4;
typedef __attribute__((ext_vector_type(4))) int int4v;

__device__ __forceinline__ float elu1(float t) {
    return t > 0.0f ? t + 1.0f : expf(t);
}
__device__ __forceinline__ float4 ld4(const float* p) { return *reinterpret_cast<const float4*>(p); }
__device__ __forceinline__ void  st4(float* p, float4 v) { *reinterpret_cast<float4*>(p) = v; }
__device__ __forceinline__ void  st4nt(float* p, float4 v) {
    v4f w; w.x = v.x; w.y = v.y; w.z = v.z; w.w = v.w;
    __builtin_nontemporal_store(w, reinterpret_cast<v4f*>(p));
}
__device__ __forceinline__ void fma4(float4& a, float s, float4 w) {
    a.x = fmaf(s, w.x, a.x); a.y = fmaf(s, w.y, a.y);
    a.z = fmaf(s, w.z, a.z); a.w = fmaf(s, w.w, a.w);
}
// RNE f32 -> bf16 (scalar, for prep kernel)
__device__ __forceinline__ short f2bf(float f) {
    unsigned u = __float_as_uint(f);
    unsigned r = 0x7FFFu + ((u >> 16) & 1u);
    return (short)((u + r) >> 16);
}
// packed f32x2 -> bf16x2 (RNE) for staging
__device__ __forceinline__ unsigned cvtpk(float a, float b) {
    unsigned r;
    asm("v_cvt_pk_bf16_f32 %0, %1, %2" : "=v"(r) : "v"(a), "v"(b));
    return r;
}

// ---------------------------------------------------------------------------
// prep: build MFMA B-fragments from Wq/Wk/Wv (bf16).
// For k-step kt, lane l holds W[kt*32 + (l>>4)*8 + j][l&15], j=0..7.
// fq: 32 kt, fk/fv: 24 kt. grid 20 x 256 threads.
// ---------------------------------------------------------------------------
__global__ __launch_bounds__(256) void prep(
    const float* __restrict__ Wq, const float* __restrict__ Wk,
    const float* __restrict__ Wv,
    short* __restrict__ fq, short* __restrict__ fk, short* __restrict__ fv)
{
    const int id = blockIdx.x * 256 + threadIdx.x;
    if (id >= 80 * 64) return;
    const int l  = id & 63;
    const int kt = id >> 6;
    const float* W; short* dst; int ktl;
    if (kt < 32)      { W = Wq; dst = fq; ktl = kt; }
    else if (kt < 56) { W = Wk; dst = fk; ktl = kt - 32; }
    else              { W = Wv; dst = fv; ktl = kt - 56; }
    const int k0 = ktl * 32 + (l >> 4) * 8;
    const int d  = l & 15;
    short* o = dst + ((size_t)ktl * 64 + l) * 8;
    #pragma unroll
    for (int j = 0; j < 8; ++j)
        o[j] = f2bf(W[(size_t)(k0 + j) * DH + d]);
}

// ---------------------------------------------------------------------------
// fused1: blocks [0,512): kvr via MFMA — K=elu1(ctx@Wk+bk), V=ctx@Wv+bv in
//   fragments, spilled to LDS, fused partial KtV(16x16)+Ksum -> part.
//         blocks [512,1024): Q = elu1(x@Wq+bq) -> q_ws via MFMA.
// x/ctx staged to LDS as bf16 (cvt_pk in flight). 4 waves, wave w owns rows
// [w*16, w*16+16). Per 32-k step: 1 ds_read_b128 (A) + B-frag ld (L1) + MFMA.
// ---------------------------------------------------------------------------
__global__ __launch_bounds__(256) void fused1(
    const float* __restrict__ ctx, const float* __restrict__ x,
    const short* __restrict__ fq, const short* __restrict__ fk,
    const short* __restrict__ fv,
    const float* __restrict__ bq, const float* __restrict__ bk,
    const float* __restrict__ bv,
    float* __restrict__ part, float* __restrict__ q_ws)
{
    __shared__ union {
        short xt[64 * XS];                              // 17408 B
        struct { float k[64][17]; float v[64][17]; } kv; // 8704 B (post-loop)
    } sh;

    const int t  = threadIdx.x;
    const int l  = t & 63;        // lane in wave
    const int w  = t >> 6;        // wave 0..3 -> rows [w*16, w*16+16)
    const int g4 = l >> 4;        // k-subgroup 0..3
    const int lr = l & 15;        // row-in-tile (A) / dim (B,D)

    float4 A[8];

// stage one 64x128 fp32 chunk -> regs (fully coalesced, 2KB/wave/step)
#define SLOADX(src, LD, ch) { \
    _Pragma("unroll") for (int i = 0; i < 4; ++i) { \
        const int fi = 2*t + i*512; \
        const int rr = fi >> 5; const int cc = fi & 31; \
        const float* p = (src) + (row0 + rr)*(LD) + (ch)*128 + cc*4; \
        A[2*i] = ld4(p); A[2*i+1] = ld4(p + 4); } }
// convert to bf16 + LDS write (16B aligned, ~2-way banks)
#define SWRITEX() { \
    _Pragma("unroll") for (int i = 0; i < 4; ++i) { \
        const int fi = 2*t + i*512; \
        const int rr = fi >> 5; const int cc = fi & 31; \
        int4v wv4; \
        wv4.x = (int)cvtpk(A[2*i].x,   A[2*i].y); \
        wv4.y = (int)cvtpk(A[2*i].z,   A[2*i].w); \
        wv4.z = (int)cvtpk(A[2*i+1].x, A[2*i+1].y); \
        wv4.w = (int)cvtpk(A[2*i+1].z, A[2*i+1].w); \
        *reinterpret_cast<int4v*>(reinterpret_cast<char*>(&sh.xt[0]) + rr*272 + cc*8) = wv4; } }

    if (blockIdx.x < B_*N_/64) {
        // ---------------- kvr path ----------------
        const size_t row0 = (size_t)blockIdx.x * 64;
        f32x4 accK = {0,0,0,0}, accV = {0,0,0,0};

        SLOADX(ctx, DC, 0);
        for (int ch = 0; ch < NCHK; ++ch) {
            SWRITEX();
            __syncthreads();
            if (ch + 1 < NCHK) SLOADX(ctx, DC, ch + 1);
            #pragma unroll
            for (int kt = 0; kt < 4; ++kt) {
                const short8v a = *reinterpret_cast<const short8v*>(
                    &sh.xt[(w*16 + lr)*XS + kt*32 + g4*8]);
                const int ktg = ch*4 + kt;
                const short8v bkf = *reinterpret_cast<const short8v*>(fk + ((size_t)ktg*64 + l)*8);
                const short8v bvf = *reinterpret_cast<const short8v*>(fv + ((size_t)ktg*64 + l)*8);
                accK = __builtin_amdgcn_mfma_f32_16x16x32_bf16(a, bkf, accK, 0, 0, 0);
                accV = __builtin_amdgcn_mfma_f32_16x16x32_bf16(a, bvf, accV, 0, 0, 0);
            }
            __syncthreads();
        }

        // epilogue: D[(l>>4)*4+j][l&15] per m89 layout -> sk/sv (union over xt)
        const float bkv = bk[lr], bvv = bv[lr];
        #pragma unroll
        for (int j = 0; j < 4; ++j) {
            const int n = w*16 + g4*4 + j;
            sh.kv.k[n][lr] = elu1(accK[j] + bkv);
            sh.kv.v[n][lr] = accV[j] + bvv;
        }
        __syncthreads();

        const int d = t >> 4, e = t & 15;
        float acc = 0.f;
        #pragma unroll 16
        for (int n = 0; n < 64; ++n) acc += sh.kv.k[n][d] * sh.kv.v[n][e];
        float* p = part + (size_t)blockIdx.x * 272;
        p[t] = acc;
        if (t < DH) {
            float ss = 0.f;
            #pragma unroll 16
            for (int n = 0; n < 64; ++n) ss += sh.kv.k[n][t];
            p[256 + t] = ss;
        }
    } else {
        // ---------------- Q path ----------------
        const size_t row0 = (size_t)(blockIdx.x - B_*N_/64) * 64;
        f32x4 accQ = {0,0,0,0};

        SLOADX(x, DM, 0);
        for (int ch = 0; ch < NCHQ; ++ch) {
            SWRITEX();
            __syncthreads();
            if (ch + 1 < NCHQ) SLOADX(x, DM, ch + 1);
            #pragma unroll
            for (int kt = 0; kt < 4; ++kt) {
                const short8v a = *reinterpret_cast<const short8v*>(
                    &sh.xt[(w*16 + lr)*XS + kt*32 + g4*8]);
                const int ktg = ch*4 + kt;
                const short8v bqf = *reinterpret_cast<const short8v*>(fq + ((size_t)ktg*64 + l)*8);
                accQ = __builtin_amdgcn_mfma_f32_16x16x32_bf16(a, bqf, accQ, 0, 0, 0);
            }
            __syncthreads();
        }

        const float bqv = bq[lr];
        #pragma unroll
        for (int j = 0; j < 4; ++j) {
            const int n = w*16 + g4*4 + j;
            q_ws[(row0 + n)*DH + lr] = elu1(accQ[j] + bqv);
        }
    }
#undef SLOADX
#undef SWRITEX
}

// ---------------------------------------------------------------------------
// reduce2: combine partials -> comb[b][272] (256 KtV d-major + 16 Ksum)
// ---------------------------------------------------------------------------
__global__ __launch_bounds__(320) void reduce2(
    const float* __restrict__ part, float* __restrict__ comb)
{
    const int b = blockIdx.x;
    const int t = threadIdx.x;
    if (t < 272) {
        float s = 0.f;
        #pragma unroll
        for (int ch = 0; ch < CHUNKS; ++ch)
            s += part[((size_t)b*CHUNKS + ch) * 272 + t];
        comb[(size_t)b*272 + t] = s;
    }
}

// ---------------------------------------------------------------------------
// oproj: o = (Q@KtV)/(Q.Ksum+1e-6); out = o@Wo + bo.
// 16 rows/block, grid = B*M/16 = 2048. Wo in regs, nt coalesced stores.
// ---------------------------------------------------------------------------
__global__ __launch_bounds__(256) void oproj(
    const float* __restrict__ q_ws, const float* __restrict__ comb,
    const float* __restrict__ Wo, const float* __restrict__ bo,
    float* __restrict__ out)
{
    __shared__ float ql[16 * DH];
    __shared__ float ol[16 * DH];
    __shared__ float kts[272];

    const int t = threadIdx.x;
    const size_t row0 = (size_t)blockIdx.x * 16;
    const int b = blockIdx.x >> 8;          // 256 blocks per batch

    float4 wreg[16];
    #pragma unroll
    for (int e = 0; e < 16; ++e) wreg[e] = ld4(Wo + (size_t)e*DM + t*4);
    const float4 bov = ld4(bo + t*4);

    if (t < 64) st4(&ql[t*4], ld4(q_ws + row0*DH + t*4));
    else if (t < 132) st4(&kts[(t-64)*4], ld4(comb + (size_t)b*272 + (t-64)*4));
    __syncthreads();

    if (t < 64) {
        const float* qrow = &ql[(t >> 2) * DH];
        const int jj = (t & 3) * 4;
        float den = 1e-6f;
        float4 num = make_float4(0,0,0,0);
        #pragma unroll
        for (int d4 = 0; d4 < 4; ++d4) {
            const float4 q4  = ld4(&qrow[d4*4]);
            const float4 ks4 = ld4(&kts[256 + d4*4]);
            den += q4.x*ks4.x + q4.y*ks4.y + q4.z*ks4.z + q4.w*ks4.w;
            fma4(num, q4.x, ld4(&kts[(d4*4+0)*DH + jj]));
            fma4(num, q4.y, ld4(&kts[(d4*4+1)*DH + jj]));
            fma4(num, q4.z, ld4(&kts[(d4*4+2)*DH + jj]));
            fma4(num, q4.w, ld4(&kts[(d4*4+3)*DH + jj]));
        }
        const float inv = 1.0f / den;
        float4 o4; o4.x = num.x*inv; o4.y = num.y*inv; o4.z = num.z*inv; o4.w = num.w*inv;
        st4(&ol[(t >> 2)*DH + jj], o4);
    }
    __syncthreads();

    #pragma unroll
    for (int r = 0; r < 16; ++r) {
        float4 a = bov;
        #pragma unroll
        for (int eo = 0; eo < 4; ++eo) {
            const float4 o4 = ld4(&ol[r*DH + eo*4]);
            fma4(a, o4.x, wreg[eo*4+0]); fma4(a, o4.y, wreg[eo*4+1]);
            fma4(a, o4.z, wreg[eo*4+2]); fma4(a, o4.w, wreg[eo*4+3]);
        }
        st4nt(out + (row0 + r)*DM + t*4, a);
    }
}

// ---------------------------------------------------------------------------
extern "C" void kernel_launch(void* const* d_in, const int* in_sizes, int n_in,
                              void* d_out, int out_size, void* d_ws, size_t ws_size,
                              hipStream_t stream) {
    const float* x    = (const float*)d_in[0];
    const float* ctx  = (const float*)d_in[1];
    const float* Wq   = (const float*)d_in[2];
    const float* bq   = (const float*)d_in[3];
    const float* Wk   = (const float*)d_in[4];
    const float* bk   = (const float*)d_in[5];
    const float* Wv   = (const float*)d_in[6];
    const float* bv   = (const float*)d_in[7];
    const float* Wo   = (const float*)d_in[8];
    const float* bo   = (const float*)d_in[9];
    float* out = (float*)d_out;

    float* ws = (float*)d_ws;
    float* part = ws;                               // 512*272 f
    float* comb = part + (size_t)512*272;           // 8*272 f
    float* q_ws = comb + (size_t)B_*272;            // 32768*16 f = 2 MB
    short* fq = (short*)(q_ws + (size_t)B_*M_*DH);  // 32*64*8 bf16
    short* fk = fq + (size_t)32*64*8;               // 24*64*8
    short* fv = fk + (size_t)24*64*8;               // 24*64*8

    prep<<<dim3(20), dim3(256), 0, stream>>>(Wq, Wk, Wv, fq, fk, fv);
    fused1<<<dim3(B_*N_/64 + B_*M_/64), dim3(256), 0, stream>>>(
        ctx, x, fq, fk, fv, bq, bk, bv, part, q_ws);
    reduce2<<<dim3(B_), dim3(320), 0, stream>>>(part, comb);
    oproj<<<dim3(B_*M_/16), dim3(256), 0, stream>>>(q_ws, comb, Wo, bo, out);
}

// Round 12
// 79.753 us; speedup vs baseline: 1.4910x; 1.0330x over previous
//
#include <hip/hip_runtime.h>
#include <math.h>

#define B_   8
#define M_   4096
#define N_   4096
#define DM   1024
#define DC   768
#define DH   16
#define CHUNKS 64
#define PD   8           // register pipeline depth (power of 2)

typedef float v4f __attribute__((ext_vector_type(4)));
typedef __attribute__((ext_vector_type(8))) short short8v;   // 8 bf16 (4 VGPR)
typedef __attribute__((ext_vector_type(4))) float f32x4;
typedef __attribute__((ext_vector_type(4))) int int4v;

__device__ __forceinline__ float elu1(float t) {
    return t > 0.0f ? t + 1.0f : expf(t);
}
__device__ __forceinline__ float4 ld4(const float* p) { return *reinterpret_cast<const float4*>(p); }
__device__ __forceinline__ void  st4(float* p, float4 v) { *reinterpret_cast<float4*>(p) = v; }
__device__ __forceinline__ void  st4nt(float* p, float4 v) {
    v4f w; w.x = v.x; w.y = v.y; w.z = v.z; w.w = v.w;
    __builtin_nontemporal_store(w, reinterpret_cast<v4f*>(p));
}
__device__ __forceinline__ void fma4(float4& a, float s, float4 w) {
    a.x = fmaf(s, w.x, a.x); a.y = fmaf(s, w.y, a.y);
    a.z = fmaf(s, w.z, a.z); a.w = fmaf(s, w.w, a.w);
}
__device__ __forceinline__ short f2bf(float f) {
    unsigned u = __float_as_uint(f);
    unsigned r = 0x7FFFu + ((u >> 16) & 1u);
    return (short)((u + r) >> 16);
}
__device__ __forceinline__ unsigned cvtpk(float a, float b) {
    unsigned r;
    asm("v_cvt_pk_bf16_f32 %0, %1, %2" : "=v"(r) : "v"(a), "v"(b));
    return r;
}
// build A-fragment (8 bf16) from two fp32 float4s
__device__ __forceinline__ short8v mk_frag(const float4& a, const float4& b) {
    int4v iv;
    iv.x = (int)cvtpk(a.x, a.y);
    iv.y = (int)cvtpk(a.z, a.w);
    iv.z = (int)cvtpk(b.x, b.y);
    iv.w = (int)cvtpk(b.z, b.w);
    union { int4v i; short8v s; } u; u.i = iv;
    return u.s;
}

// ---------------------------------------------------------------------------
// prep: build MFMA B-fragments from Wq/Wk/Wv (bf16).
// For k-step kt, lane l holds W[kt*32 + (l>>4)*8 + j][l&15], j=0..7.
// ---------------------------------------------------------------------------
__global__ __launch_bounds__(256) void prep(
    const float* __restrict__ Wq, const float* __restrict__ Wk,
    const float* __restrict__ Wv,
    short* __restrict__ fq, short* __restrict__ fk, short* __restrict__ fv)
{
    const int id = blockIdx.x * 256 + threadIdx.x;
    if (id >= 80 * 64) return;
    const int l  = id & 63;
    const int kt = id >> 6;
    const float* W; short* dst; int ktl;
    if (kt < 32)      { W = Wq; dst = fq; ktl = kt; }
    else if (kt < 56) { W = Wk; dst = fk; ktl = kt - 32; }
    else              { W = Wv; dst = fv; ktl = kt - 56; }
    const int k0 = ktl * 32 + (l >> 4) * 8;
    const int d  = l & 15;
    short* o = dst + ((size_t)ktl * 64 + l) * 8;
    #pragma unroll
    for (int j = 0; j < 8; ++j)
        o[j] = f2bf(W[(size_t)(k0 + j) * DH + d]);
}

// ---------------------------------------------------------------------------
// fused1 v2: barrier-free MFMA-from-global.
// blocks [0,512): kvr — K=elu1(ctx@Wk+bk), V=ctx@Wv+bv via MFMA, then fused
//   partial KtV(16x16)+Ksum -> part (small LDS epilogue only).
// blocks [512,1024): Q = elu1(x@Wq+bq) -> q_ws via MFMA.
// Each lane loads its own A-fragment source (16B x2 fp32) directly from
// global, cvt_pk -> bf16, 8-deep register pipeline, NO main-loop barriers.
// ---------------------------------------------------------------------------
__global__ __launch_bounds__(256) void fused1(
    const float* __restrict__ ctx, const float* __restrict__ x,
    const short* __restrict__ fq, const short* __restrict__ fk,
    const short* __restrict__ fv,
    const float* __restrict__ bq, const float* __restrict__ bk,
    const float* __restrict__ bv,
    float* __restrict__ part, float* __restrict__ q_ws)
{
    __shared__ float sk[64][DH+1];
    __shared__ float sv[64][DH+1];

    const int t  = threadIdx.x;
    const int l  = t & 63;        // lane in wave
    const int w  = t >> 6;        // wave 0..3 -> rows [w*16, w*16+16)
    const int g4 = l >> 4;        // k-subgroup 0..3
    const int lr = l & 15;        // row-in-tile (A) / dim (B,D)

    float4 pa[PD], pb[PD];

    if (blockIdx.x < B_*N_/64) {
        // ---------------- kvr path: 24 kt steps over DC=768 ----------------
        const size_t row0 = (size_t)blockIdx.x * 64;
        const float* src = ctx + (row0 + w*16 + lr) * DC + g4*8;
        f32x4 accK = {0,0,0,0}, accV = {0,0,0,0};

        #pragma unroll
        for (int i = 0; i < PD; ++i) {
            pa[i] = ld4(src + i*32);
            pb[i] = ld4(src + i*32 + 4);
        }
        #pragma unroll
        for (int kt = 0; kt < 24; ++kt) {
            const int st = kt & (PD-1);
            const short8v a = mk_frag(pa[st], pb[st]);
            if (kt + PD < 24) {
                pa[st] = ld4(src + (kt+PD)*32);
                pb[st] = ld4(src + (kt+PD)*32 + 4);
            }
            const short8v bkf = *reinterpret_cast<const short8v*>(fk + ((size_t)kt*64 + l)*8);
            const short8v bvf = *reinterpret_cast<const short8v*>(fv + ((size_t)kt*64 + l)*8);
            accK = __builtin_amdgcn_mfma_f32_16x16x32_bf16(a, bkf, accK, 0, 0, 0);
            accV = __builtin_amdgcn_mfma_f32_16x16x32_bf16(a, bvf, accV, 0, 0, 0);
        }

        // epilogue: D[(l>>4)*4+j][l&15] -> sk/sv, then 16x16 KtV + Ksum
        const float bkv = bk[lr], bvv = bv[lr];
        #pragma unroll
        for (int j = 0; j < 4; ++j) {
            const int n = w*16 + g4*4 + j;
            sk[n][lr] = elu1(accK[j] + bkv);
            sv[n][lr] = accV[j] + bvv;
        }
        __syncthreads();

        const int d = t >> 4, e = t & 15;
        float acc = 0.f;
        #pragma unroll 16
        for (int n = 0; n < 64; ++n) acc += sk[n][d] * sv[n][e];
        float* p = part + (size_t)blockIdx.x * 272;
        p[t] = acc;
        if (t < DH) {
            float ss = 0.f;
            #pragma unroll 16
            for (int n = 0; n < 64; ++n) ss += sk[n][t];
            p[256 + t] = ss;
        }
    } else {
        // ---------------- Q path: 32 kt steps over DM=1024 ----------------
        const size_t row0 = (size_t)(blockIdx.x - B_*N_/64) * 64;
        const float* src = x + (row0 + w*16 + lr) * DM + g4*8;
        f32x4 accQ = {0,0,0,0};

        #pragma unroll
        for (int i = 0; i < PD; ++i) {
            pa[i] = ld4(src + i*32);
            pb[i] = ld4(src + i*32 + 4);
        }
        #pragma unroll
        for (int kt = 0; kt < 32; ++kt) {
            const int st = kt & (PD-1);
            const short8v a = mk_frag(pa[st], pb[st]);
            if (kt + PD < 32) {
                pa[st] = ld4(src + (kt+PD)*32);
                pb[st] = ld4(src + (kt+PD)*32 + 4);
            }
            const short8v bqf = *reinterpret_cast<const short8v*>(fq + ((size_t)kt*64 + l)*8);
            accQ = __builtin_amdgcn_mfma_f32_16x16x32_bf16(a, bqf, accQ, 0, 0, 0);
        }

        const float bqv = bq[lr];
        #pragma unroll
        for (int j = 0; j < 4; ++j) {
            const int n = w*16 + g4*4 + j;
            q_ws[(row0 + n)*DH + lr] = elu1(accQ[j] + bqv);
        }
    }
}

// ---------------------------------------------------------------------------
// reduce2: combine partials -> comb[b][272] (256 KtV d-major + 16 Ksum)
// ---------------------------------------------------------------------------
__global__ __launch_bounds__(320) void reduce2(
    const float* __restrict__ part, float* __restrict__ comb)
{
    const int b = blockIdx.x;
    const int t = threadIdx.x;
    if (t < 272) {
        float s = 0.f;
        #pragma unroll
        for (int ch = 0; ch < CHUNKS; ++ch)
            s += part[((size_t)b*CHUNKS + ch) * 272 + t];
        comb[(size_t)b*272 + t] = s;
    }
}

// ---------------------------------------------------------------------------
// oproj: o = (Q@KtV)/(Q.Ksum+1e-6); out = o@Wo + bo.
// 16 rows/block, grid = B*M/16 = 2048. Wo in regs, nt coalesced stores.
// ---------------------------------------------------------------------------
__global__ __launch_bounds__(256) void oproj(
    const float* __restrict__ q_ws, const float* __restrict__ comb,
    const float* __restrict__ Wo, const float* __restrict__ bo,
    float* __restrict__ out)
{
    __shared__ float ql[16 * DH];
    __shared__ float ol[16 * DH];
    __shared__ float kts[272];

    const int t = threadIdx.x;
    const size_t row0 = (size_t)blockIdx.x * 16;
    const int b = blockIdx.x >> 8;          // 256 blocks per batch

    float4 wreg[16];
    #pragma unroll
    for (int e = 0; e < 16; ++e) wreg[e] = ld4(Wo + (size_t)e*DM + t*4);
    const float4 bov = ld4(bo + t*4);

    if (t < 64) st4(&ql[t*4], ld4(q_ws + row0*DH + t*4));
    else if (t < 132) st4(&kts[(t-64)*4], ld4(comb + (size_t)b*272 + (t-64)*4));
    __syncthreads();

    if (t < 64) {
        const float* qrow = &ql[(t >> 2) * DH];
        const int jj = (t & 3) * 4;
        float den = 1e-6f;
        float4 num = make_float4(0,0,0,0);
        #pragma unroll
        for (int d4 = 0; d4 < 4; ++d4) {
            const float4 q4  = ld4(&qrow[d4*4]);
            const float4 ks4 = ld4(&kts[256 + d4*4]);
            den += q4.x*ks4.x + q4.y*ks4.y + q4.z*ks4.z + q4.w*ks4.w;
            fma4(num, q4.x, ld4(&kts[(d4*4+0)*DH + jj]));
            fma4(num, q4.y, ld4(&kts[(d4*4+1)*DH + jj]));
            fma4(num, q4.z, ld4(&kts[(d4*4+2)*DH + jj]));
            fma4(num, q4.w, ld4(&kts[(d4*4+3)*DH + jj]));
        }
        const float inv = 1.0f / den;
        float4 o4; o4.x = num.x*inv; o4.y = num.y*inv; o4.z = num.z*inv; o4.w = num.w*inv;
        st4(&ol[(t >> 2)*DH + jj], o4);
    }
    __syncthreads();

    #pragma unroll
    for (int r = 0; r < 16; ++r) {
        float4 a = bov;
        #pragma unroll
        for (int eo = 0; eo < 4; ++eo) {
            const float4 o4 = ld4(&ol[r*DH + eo*4]);
            fma4(a, o4.x, wreg[eo*4+0]); fma4(a, o4.y, wreg[eo*4+1]);
            fma4(a, o4.z, wreg[eo*4+2]); fma4(a, o4.w, wreg[eo*4+3]);
        }
        st4nt(out + (row0 + r)*DM + t*4, a);
    }
}

// ---------------------------------------------------------------------------
extern "C" void kernel_launch(void* const* d_in, const int* in_sizes, int n_in,
                              void* d_out, int out_size, void* d_ws, size_t ws_size,
                              hipStream_t stream) {
    const float* x    = (const float*)d_in[0];
    const float* ctx  = (const float*)d_in[1];
    const float* Wq   = (const float*)d_in[2];
    const float* bq   = (const float*)d_in[3];
    const float* Wk   = (const float*)d_in[4];
    const float* bk   = (const float*)d_in[5];
    const float* Wv   = (const float*)d_in[6];
    const float* bv   = (const float*)d_in[7];
    const float* Wo   = (const float*)d_in[8];
    const float* bo   = (const float*)d_in[9];
    float* out = (float*)d_out;

    float* ws = (float*)d_ws;
    float* part = ws;                               // 512*272 f
    float* comb = part + (size_t)512*272;           // 8*272 f
    float* q_ws = comb + (size_t)B_*272;            // 32768*16 f = 2 MB
    short* fq = (short*)(q_ws + (size_t)B_*M_*DH);  // 32*64*8 bf16
    short* fk = fq + (size_t)32*64*8;               // 24*64*8
    short* fv = fk + (size_t)24*64*8;               // 24*64*8

    prep<<<dim3(20), dim3(256), 0, stream>>>(Wq, Wk, Wv, fq, fk, fv);
    fused1<<<dim3(B_*N_/64 + B_*M_/64), dim3(256), 0, stream>>>(
        ctx, x, fq, fk, fv, bq, bk, bv, part, q_ws);
    reduce2<<<dim3(B_), dim3(320), 0, stream>>>(part, comb);
    oproj<<<dim3(B_*M_/16), dim3(256), 0, stream>>>(q_ws, comb, Wo, bo, out);
}